// Round 3
// baseline (3616.954 us; speedup 1.0000x reference)
//
#include <hip/hip_runtime.h>
#include <stdint.h>

// Problem dims
#define TS  256
#define CTS 512
#define BB  64
#define HH  512
#define KK  10

typedef short short8 __attribute__((ext_vector_type(8)));
typedef float floatx4 __attribute__((ext_vector_type(4)));

__device__ __forceinline__ unsigned short f2bf(float f) {
  unsigned u = __float_as_uint(f);
  unsigned r = (u + 0x7fffu + ((u >> 16) & 1u)) >> 16;  // RNE
  return (unsigned short)r;
}

// ---------------------------------------------------------------------------
// K1: Wcat [2048][1024] bf16.
// Row groups of 512: g0 = r-gate [W_hh_r | W_ih_r]; g1 = z-gate [W_hh_z | W_ih_z];
// g2 = i_n [0 | W_ih_n]; g3 = h_n [W_hh_n | 0]. (n-gate split because n = tanh(i_n + r*h_n))
__global__ void k_wcat(const float* __restrict__ W_ih, const float* __restrict__ W_hh,
                       unsigned short* __restrict__ Wcat) {
  int idx = blockIdx.x * 256 + threadIdx.x;  // 2048*1024 total
  int r = idx >> 10, c = idx & 1023;
  int g = r >> 9, j = r & 511;
  float v;
  if (g == 0)      v = (c < 512) ? W_hh[j * 512 + c]          : W_ih[j * 512 + (c - 512)];
  else if (g == 1) v = (c < 512) ? W_hh[(512 + j) * 512 + c]  : W_ih[(512 + j) * 512 + (c - 512)];
  else if (g == 2) v = (c < 512) ? 0.f                        : W_ih[(1024 + j) * 512 + (c - 512)];
  else             v = (c < 512) ? W_hh[(1024 + j) * 512 + c] : 0.f;
  Wcat[idx] = f2bf(v);
}

// ---------------------------------------------------------------------------
// K2: G[t*64+b][30] = exp(x_t[b] @ {Wa;Wb;Wk}.T + bias). One wave per (t,b) row.
__global__ void k_abk(const float* __restrict__ inp,
                      const float* __restrict__ Wa, const float* __restrict__ ba,
                      const float* __restrict__ Wb, const float* __restrict__ bvb,
                      const float* __restrict__ Wk, const float* __restrict__ bk,
                      float* __restrict__ G) {
  int row = blockIdx.x;                 // t*64 + b
  int lane = threadIdx.x;               // 0..63
  int j = lane & 31, half = lane >> 5;  // j = output idx, half = K-half
  const float* Wrow; float bias;
  if (j < 10)      { Wrow = Wa + j * 512;        bias = ba[j]; }
  else if (j < 20) { Wrow = Wb + (j - 10) * 512; bias = bvb[j - 10]; }
  else if (j < 30) { Wrow = Wk + (j - 20) * 512; bias = bk[j - 20]; }
  else             { Wrow = Wa;                  bias = 0.f; }
  const float4* x4 = (const float4*)(inp + row * 512 + half * 256);
  const float4* w4 = (const float4*)(Wrow + half * 256);
  float acc = 0.f;
#pragma unroll 8
  for (int i = 0; i < 64; ++i) {
    float4 a = x4[i], w = w4[i];
    acc += a.x * w.x + a.y * w.y + a.z * w.z + a.w * w.w;
  }
  acc += __shfl_down(acc, 32, 64);  // fold the two K-halves
  if (lane < 30) G[row * 30 + lane] = __expf(acc + bias);
}

// ---------------------------------------------------------------------------
// K3: k_t cumsum over t for each (b,k) — parallel Hillis-Steele scan per b.
__global__ __launch_bounds__(256) void k_cumsum(
    const float* __restrict__ G, const float* __restrict__ att_init,
    float* __restrict__ out_k) {
  int b = blockIdx.x;       // 64 blocks
  int t = threadIdx.x;      // 256 = TS
  __shared__ float sb[2][256];
  for (int k = 0; k < KK; ++k) {
    float v = G[(t * BB + b) * 30 + 20 + k];
    sb[0][t] = v;
    __syncthreads();
    int src = 0;
#pragma unroll
    for (int d = 1; d < 256; d <<= 1) {
      float add = (t >= d) ? sb[src][t - d] : 0.f;
      float cur = sb[src][t];
      __syncthreads();
      sb[1 - src][t] = cur + add;
      src = 1 - src;
      __syncthreads();
    }
    out_k[(t * BB + b) * KK + k] = att_init[b * KK + k] + sb[src][t];
    __syncthreads();
  }
}

// ---------------------------------------------------------------------------
// K4: phi[b][t][s] = sum_k a*exp(-b*(k_t - s)^2), stored bf16 (A-matrix of att_w GEMM).
__global__ void k_phi(const float* __restrict__ G, const float* __restrict__ attk,
                      unsigned short* __restrict__ phi_bf) {
  int t = blockIdx.x, b = blockIdx.y;
  int row = t * BB + b;
  float a[10], bv[10], kt[10];
#pragma unroll
  for (int k = 0; k < 10; ++k) {
    a[k]  = G[row * 30 + k];
    bv[k] = G[row * 30 + 10 + k];
    kt[k] = attk[row * KK + k];
  }
#pragma unroll
  for (int e = 0; e < 2; ++e) {
    int s = threadIdx.x + e * 256;
    float fs = (float)s;
    float ph = 0.f;
#pragma unroll
    for (int k = 0; k < 10; ++k) {
      float d = kt[k] - fs;
      ph += a[k] * __expf(-bv[k] * d * d);
    }
    phi_bf[(b * TS + t) * CTS + s] = f2bf(ph);
  }
}

// ---------------------------------------------------------------------------
// K5: att_w[t][b][h] = sum_s phi[b][t][s] * c_inp[s][b][h].
// Per-b GEMM [256x512]@[512x512], MFMA 16x16x32 bf16. Block = (h-tile 64, t-tile 64, b).
__global__ __launch_bounds__(256) void k_attw(
    const float* __restrict__ c_inp, const unsigned short* __restrict__ phi_bf,
    float* __restrict__ out_w, unsigned short* __restrict__ attw_bf) {
  int h0 = blockIdx.x * 64;
  int t0 = blockIdx.y * 64;
  int b  = blockIdx.z;
  int tid = threadIdx.x;
  int lane = tid & 63, wv = tid >> 6;
  int x = lane & 15, q = lane >> 4;
  __shared__ __align__(16) unsigned short Bt[64 * 40];  // [h_local][s_local], stride 40 (pad)
  floatx4 acc[4];
#pragma unroll
  for (int m = 0; m < 4; ++m) acc[m] = (floatx4){0.f, 0.f, 0.f, 0.f};
  int s_l = tid >> 3, h8 = (tid & 7) * 8;
  for (int ss = 0; ss < 16; ++ss) {
    int s0 = ss * 32;
    const float* src = c_inp + ((s0 + s_l) * BB + b) * HH + h0 + h8;
    float4 v0 = *(const float4*)src;
    float4 v1 = *(const float4*)(src + 4);
    Bt[(h8 + 0) * 40 + s_l] = f2bf(v0.x);
    Bt[(h8 + 1) * 40 + s_l] = f2bf(v0.y);
    Bt[(h8 + 2) * 40 + s_l] = f2bf(v0.z);
    Bt[(h8 + 3) * 40 + s_l] = f2bf(v0.w);
    Bt[(h8 + 4) * 40 + s_l] = f2bf(v1.x);
    Bt[(h8 + 5) * 40 + s_l] = f2bf(v1.y);
    Bt[(h8 + 6) * 40 + s_l] = f2bf(v1.z);
    Bt[(h8 + 7) * 40 + s_l] = f2bf(v1.w);
    __syncthreads();
    short8 bfrag = *(const short8*)(Bt + (wv * 16 + x) * 40 + q * 8);
#pragma unroll
    for (int mt = 0; mt < 4; ++mt) {
      short8 af = *(const short8*)(phi_bf + (b * TS + t0 + mt * 16 + x) * CTS + s0 + q * 8);
      acc[mt] = __builtin_amdgcn_mfma_f32_16x16x32_bf16(af, bfrag, acc[mt], 0, 0, 0);
    }
    __syncthreads();
  }
#pragma unroll
  for (int mt = 0; mt < 4; ++mt)
#pragma unroll
    for (int r = 0; r < 4; ++r) {
      int t_l = mt * 16 + q * 4 + r;           // C/D: row = quad*4+reg
      int row = (t0 + t_l) * BB + b;
      int col = h0 + wv * 16 + x;              // C/D: col = lane&15
      float v = acc[mt][r];
      out_w[row * HH + col] = v;
      attw_bf[row * HH + col] = f2bf(v);
    }
}

// ---------------------------------------------------------------------------
// K6 v3: persistent sequential GRU. 32 WGs (cooperative); WG w owns h-dims
// [w*16, w*16+16) across all 4 gate groups (64 Wcat rows, full K=1024).
// h exchange: publish = sc1 atomic stores (512/WG, cheap) + vmcnt drain + flag;
// consume = flag poll + agent ACQUIRE fence (buffer_inv) + NORMAL dwordx4 loads.
// This removes the 8192 per-lane atomic loads/WG/step that bottlenecked v1/v2.
__global__ __launch_bounds__(256, 1) void k_seq(
    const unsigned short* __restrict__ attw_bf, const unsigned short* __restrict__ Wcat,
    const float* __restrict__ gru_init, const float* __restrict__ b_ih,
    const float* __restrict__ b_hh,
    unsigned short* __restrict__ h_buf, unsigned* __restrict__ flags,
    float* __restrict__ hid_out) {
  const int w = blockIdx.x;        // 0..31
  const int j0 = w * 16;           // h-dims owned
  const int tid = threadIdx.x;
  const int lane = tid & 63, wv = tid >> 6;   // wv = gate group
  const int x = lane & 15, q = lane >> 4;

  __shared__ __align__(16) unsigned short hs[64 * 520];  // staged h_{t-1}; stride 520 = 2-way (free)
  __shared__ float gbuf[64 * 68];                        // [b][n = g*16 + jl]
  __shared__ float bsum[64];

  // Weight B-fragments: Wcat row = wv*512 + j0 + x, full K (32 kk-chunks of 32).
  short8 wfrag[32];
  {
    const unsigned short* wr = Wcat + (wv * 512 + j0 + x) * 1024;
#pragma unroll
    for (int kk = 0; kk < 32; ++kk)
      wfrag[kk] = *(const short8*)(wr + kk * 32 + q * 8);
  }
  if (tid < 64) {
    int g = tid >> 4, jl = tid & 15, j = j0 + jl;
    float v;
    if (g == 0)      v = b_ih[j] + b_hh[j];
    else if (g == 1) v = b_ih[512 + j] + b_hh[512 + j];
    else if (g == 2) v = b_ih[1024 + j];
    else             v = b_hh[1024 + j];
    bsum[tid] = v;
  }
  __syncthreads();
  const float bias_n = bsum[wv * 16 + x];  // bias folded into acc init

  // This thread's gate cells: (bo, jl0), (bo, jl0+1), (bo+32, jl0), (bo+32, jl0+1)
  const int bo = tid >> 3, jl0 = (tid & 7) * 2;
  float hp[4];
  hp[0] = gru_init[bo * HH + j0 + jl0];
  hp[1] = gru_init[bo * HH + j0 + jl0 + 1];
  hp[2] = gru_init[(bo + 32) * HH + j0 + jl0];
  hp[3] = gru_init[(bo + 32) * HH + j0 + jl0 + 1];
  {
    unsigned p0 = (unsigned)f2bf(hp[0]) | ((unsigned)f2bf(hp[1]) << 16);
    unsigned p1 = (unsigned)f2bf(hp[2]) | ((unsigned)f2bf(hp[3]) << 16);
    __hip_atomic_store((unsigned*)(h_buf + bo * HH + j0 + jl0), p0,
                       __ATOMIC_RELAXED, __HIP_MEMORY_SCOPE_AGENT);
    __hip_atomic_store((unsigned*)(h_buf + (bo + 32) * HH + j0 + jl0), p1,
                       __ATOMIC_RELAXED, __HIP_MEMORY_SCOPE_AGENT);
  }
  __builtin_amdgcn_s_waitcnt(0);  // h stores at MALL before flag
  __syncthreads();
  if (tid == 0)
    __hip_atomic_store(&flags[w * 32], 1u, __ATOMIC_RELAXED, __HIP_MEMORY_SCOPE_AGENT);

  for (int t = 0; t < TS; ++t) {
    floatx4 acc[4];
#pragma unroll
    for (int m = 0; m < 4; ++m) acc[m] = (floatx4){bias_n, bias_n, bias_n, bias_n};

    // --- w-part (K 512..1023): independent of h_{t-1}; overlaps the wait. ---
    const unsigned short* aw = attw_bf + (size_t)t * (BB * HH);
#pragma unroll
    for (int kk = 0; kk < 16; ++kk) {
#pragma unroll
      for (int m = 0; m < 4; ++m) {
        short8 af = *(const short8*)(aw + (m * 16 + x) * HH + kk * 32 + q * 8);
        acc[m] = __builtin_amdgcn_mfma_f32_16x16x32_bf16(af, wfrag[16 + kk], acc[m], 0, 0, 0);
      }
    }

    // --- wait for all WGs to publish h_{t-1} ---
    if (tid < 32) {
      while (__hip_atomic_load(&flags[tid * 32], __ATOMIC_RELAXED,
                               __HIP_MEMORY_SCOPE_AGENT) < (unsigned)(t + 1)) {}
    }
    __syncthreads();
    // Make other WGs' h stores (at MALL) visible to NORMAL vector loads:
    // emits the L1/L2 invalidate required at agent scope.
    __builtin_amdgcn_fence(__ATOMIC_ACQUIRE, "agent");

    // --- stage h_{t-1} (64x512 bf16 = 64 KB) into LDS with wide normal loads ---
    const unsigned short* hsrc = h_buf + (t & 1) * (BB * HH);
    {
      const ulonglong2* h16 = (const ulonglong2*)hsrc;  // 4096 16B chunks
      ulonglong2 tmp[16];
#pragma unroll
      for (int i = 0; i < 16; ++i) tmp[i] = h16[tid + i * 256];
#pragma unroll
      for (int i = 0; i < 16; ++i) {
        int c = tid + i * 256;
        int b = c >> 6, col = (c & 63) * 8;  // 64 chunks of 8 shorts per 512-row
        *(ulonglong2*)(hs + b * 520 + col) = tmp[i];
      }
    }
    __syncthreads();

    // --- h-part (K 0..511) from LDS ---
#pragma unroll
    for (int kk = 0; kk < 16; ++kk) {
#pragma unroll
      for (int m = 0; m < 4; ++m) {
        short8 af = *(const short8*)(hs + (m * 16 + x) * 520 + kk * 32 + q * 8);
        acc[m] = __builtin_amdgcn_mfma_f32_16x16x32_bf16(af, wfrag[kk], acc[m], 0, 0, 0);
      }
    }

    // --- scatter pre-activations: gbuf[b][wv*16 + x] ---
#pragma unroll
    for (int m = 0; m < 4; ++m)
#pragma unroll
      for (int r = 0; r < 4; ++r)
        gbuf[(m * 16 + q * 4 + r) * 68 + wv * 16 + x] = acc[m][r];
    __syncthreads();

    // --- gates for this thread's 4 cells ---
    unsigned short* hdst = h_buf + ((t + 1) & 1) * (BB * HH);
    float hn_[4];
#pragma unroll
    for (int e = 0; e < 4; ++e) {
      int b = bo + (e >> 1) * 32, jl = jl0 + (e & 1);
      const float* gb = gbuf + b * 68;
      float rp = gb[jl];
      float zp = gb[16 + jl];
      float ip = gb[32 + jl];
      float hn = gb[48 + jl];
      float r_ = 1.f / (1.f + __expf(-rp));
      float z_ = 1.f / (1.f + __expf(-zp));
      float n_ = tanhf(ip + r_ * hn);
      float hv = (1.f - z_) * n_ + z_ * hp[e];
      hn_[e] = hv;
      hid_out[((size_t)t * BB + b) * HH + j0 + jl] = hv;
    }
#pragma unroll
    for (int e = 0; e < 4; ++e) hp[e] = hn_[e];
    {
      unsigned p0 = (unsigned)f2bf(hp[0]) | ((unsigned)f2bf(hp[1]) << 16);
      unsigned p1 = (unsigned)f2bf(hp[2]) | ((unsigned)f2bf(hp[3]) << 16);
      __hip_atomic_store((unsigned*)(hdst + bo * HH + j0 + jl0), p0,
                         __ATOMIC_RELAXED, __HIP_MEMORY_SCOPE_AGENT);
      __hip_atomic_store((unsigned*)(hdst + (bo + 32) * HH + j0 + jl0), p1,
                         __ATOMIC_RELAXED, __HIP_MEMORY_SCOPE_AGENT);
    }
    __builtin_amdgcn_s_waitcnt(0);  // publishes + hid_out drained
    __syncthreads();
    if (tid == 0)
      __hip_atomic_store(&flags[w * 32], (unsigned)(t + 2),
                         __ATOMIC_RELAXED, __HIP_MEMORY_SCOPE_AGENT);
  }
}

// ---------------------------------------------------------------------------
extern "C" void kernel_launch(void* const* d_in, const int* in_sizes, int n_in,
                              void* d_out, int out_size, void* d_ws, size_t ws_size,
                              hipStream_t stream) {
  const float* c_inp    = (const float*)d_in[0];
  const float* inp      = (const float*)d_in[1];
  const float* gru_init = (const float*)d_in[2];
  const float* att_init = (const float*)d_in[3];
  const float* Wa = (const float*)d_in[4];
  const float* ba = (const float*)d_in[5];
  const float* Wb = (const float*)d_in[6];
  const float* bvb = (const float*)d_in[7];
  const float* Wk = (const float*)d_in[8];
  const float* bk = (const float*)d_in[9];
  const float* W_ih = (const float*)d_in[10];
  const float* b_ih = (const float*)d_in[11];
  const float* W_hh = (const float*)d_in[12];
  const float* b_hh = (const float*)d_in[13];

  float* out_h = (float*)d_out;                     // hiddens [256,64,512]
  float* out_k = out_h + TS * BB * HH;              // att_k   [256,64,10]
  float* out_w = out_k + TS * BB * KK;              // att_w   [256,64,512]

  char* ws = (char*)d_ws;
  float* G             = (float*)(ws);                              //  7.5 MB
  unsigned short* Wcat = (unsigned short*)(ws + 8388608);           //  4   MB
  unsigned short* phi  = (unsigned short*)(ws + 12582912);          // 16   MB
  unsigned short* awb  = (unsigned short*)(ws + 29360128);          // 16   MB
  unsigned short* hbuf = (unsigned short*)(ws + 46137344);          // 128  KB
  unsigned* flags      = (unsigned*)(ws + 46268416);                //  8   KB

  hipMemsetAsync(flags, 0, 64 * 128, stream);
  hipLaunchKernelGGL(k_wcat, dim3(8192), dim3(256), 0, stream, W_ih, W_hh, Wcat);
  hipLaunchKernelGGL(k_abk, dim3(TS * BB), dim3(64), 0, stream,
                     inp, Wa, ba, Wb, bvb, Wk, bk, G);
  hipLaunchKernelGGL(k_cumsum, dim3(BB), dim3(256), 0, stream, G, att_init, out_k);
  hipLaunchKernelGGL(k_phi, dim3(TS, BB), dim3(256), 0, stream, G, out_k, phi);
  hipLaunchKernelGGL(k_attw, dim3(8, 4, BB), dim3(256), 0, stream, c_inp, phi, out_w, awb);

  const unsigned short* a_awb = awb;
  const unsigned short* a_wc = Wcat;
  const float* a_gi = gru_init;
  const float* a_bih = b_ih;
  const float* a_bhh = b_hh;
  unsigned short* a_hb = hbuf;
  unsigned* a_fl = flags;
  float* a_oh = out_h;
  void* args[] = { (void*)&a_awb, (void*)&a_wc, (void*)&a_gi, (void*)&a_bih,
                   (void*)&a_bhh, (void*)&a_hb, (void*)&a_fl, (void*)&a_oh };
  hipLaunchCooperativeKernel((const void*)k_seq, dim3(32), dim3(256), args, 0, stream);
}

// Round 4
// 1764.458 us; speedup vs baseline: 2.0499x; 2.0499x over previous
//
#include <hip/hip_runtime.h>
#include <stdint.h>

// Problem dims
#define TS  256
#define CTS 512
#define BB  64
#define HH  512
#define KK  10

typedef short short8 __attribute__((ext_vector_type(8)));
typedef float floatx4 __attribute__((ext_vector_type(4)));

__device__ __forceinline__ unsigned short f2bf(float f) {
  unsigned u = __float_as_uint(f);
  unsigned r = (u + 0x7fffu + ((u >> 16) & 1u)) >> 16;  // RNE
  return (unsigned short)r;
}

// global -> LDS async, 16 B/lane. LDS dst = base + lane*16 (HW rule).
typedef __attribute__((address_space(1))) const unsigned int gas_u32;
typedef __attribute__((address_space(3))) unsigned int las_u32;
__device__ __forceinline__ void gll16_c(const void* g, void* l) {   // cached (L1 ok)
  __builtin_amdgcn_global_load_lds((gas_u32*)g, (las_u32*)l, 16, 0, 0);
}
__device__ __forceinline__ void gll16_sc0(const void* g, void* l) { // bypass L1, read L2
  __builtin_amdgcn_global_load_lds((gas_u32*)g, (las_u32*)l, 16, 0, 1);
}

// ---------------------------------------------------------------------------
// K1: Wcat [2048][1024] bf16.
// Row groups of 512: g0 = r-gate [W_hh_r | W_ih_r]; g1 = z-gate [W_hh_z | W_ih_z];
// g2 = i_n [0 | W_ih_n]; g3 = h_n [W_hh_n | 0]. (n = tanh(i_n + r*h_n) needs the split)
__global__ void k_wcat(const float* __restrict__ W_ih, const float* __restrict__ W_hh,
                       unsigned short* __restrict__ Wcat) {
  int idx = blockIdx.x * 256 + threadIdx.x;  // 2048*1024 total
  int r = idx >> 10, c = idx & 1023;
  int g = r >> 9, j = r & 511;
  float v;
  if (g == 0)      v = (c < 512) ? W_hh[j * 512 + c]          : W_ih[j * 512 + (c - 512)];
  else if (g == 1) v = (c < 512) ? W_hh[(512 + j) * 512 + c]  : W_ih[(512 + j) * 512 + (c - 512)];
  else if (g == 2) v = (c < 512) ? 0.f                        : W_ih[(1024 + j) * 512 + (c - 512)];
  else             v = (c < 512) ? W_hh[(1024 + j) * 512 + c] : 0.f;
  Wcat[idx] = f2bf(v);
}

// ---------------------------------------------------------------------------
// K2: G[t*64+b][30] = exp(x_t[b] @ {Wa;Wb;Wk}.T + bias). One wave per (t,b) row.
__global__ void k_abk(const float* __restrict__ inp,
                      const float* __restrict__ Wa, const float* __restrict__ ba,
                      const float* __restrict__ Wb, const float* __restrict__ bvb,
                      const float* __restrict__ Wk, const float* __restrict__ bk,
                      float* __restrict__ G) {
  int row = blockIdx.x;                 // t*64 + b
  int lane = threadIdx.x;               // 0..63
  int j = lane & 31, half = lane >> 5;  // j = output idx, half = K-half
  const float* Wrow; float bias;
  if (j < 10)      { Wrow = Wa + j * 512;        bias = ba[j]; }
  else if (j < 20) { Wrow = Wb + (j - 10) * 512; bias = bvb[j - 10]; }
  else if (j < 30) { Wrow = Wk + (j - 20) * 512; bias = bk[j - 20]; }
  else             { Wrow = Wa;                  bias = 0.f; }
  const float4* x4 = (const float4*)(inp + row * 512 + half * 256);
  const float4* w4 = (const float4*)(Wrow + half * 256);
  float acc = 0.f;
#pragma unroll 8
  for (int i = 0; i < 64; ++i) {
    float4 a = x4[i], w = w4[i];
    acc += a.x * w.x + a.y * w.y + a.z * w.z + a.w * w.w;
  }
  acc += __shfl_down(acc, 32, 64);  // fold the two K-halves
  if (lane < 30) G[row * 30 + lane] = __expf(acc + bias);
}

// ---------------------------------------------------------------------------
// K3: k_t cumsum over t for each (b,k) — parallel Hillis-Steele scan per b.
__global__ __launch_bounds__(256) void k_cumsum(
    const float* __restrict__ G, const float* __restrict__ att_init,
    float* __restrict__ out_k) {
  int b = blockIdx.x;       // 64 blocks
  int t = threadIdx.x;      // 256 = TS
  __shared__ float sb[2][256];
  for (int k = 0; k < KK; ++k) {
    float v = G[(t * BB + b) * 30 + 20 + k];
    sb[0][t] = v;
    __syncthreads();
    int src = 0;
#pragma unroll
    for (int d = 1; d < 256; d <<= 1) {
      float add = (t >= d) ? sb[src][t - d] : 0.f;
      float cur = sb[src][t];
      __syncthreads();
      sb[1 - src][t] = cur + add;
      src = 1 - src;
      __syncthreads();
    }
    out_k[(t * BB + b) * KK + k] = att_init[b * KK + k] + sb[src][t];
    __syncthreads();
  }
}

// ---------------------------------------------------------------------------
// K4: phi[b][t][s] = sum_k a*exp(-b*(k_t - s)^2), stored bf16.
__global__ void k_phi(const float* __restrict__ G, const float* __restrict__ attk,
                      unsigned short* __restrict__ phi_bf) {
  int t = blockIdx.x, b = blockIdx.y;
  int row = t * BB + b;
  float a[10], bv[10], kt[10];
#pragma unroll
  for (int k = 0; k < 10; ++k) {
    a[k]  = G[row * 30 + k];
    bv[k] = G[row * 30 + 10 + k];
    kt[k] = attk[row * KK + k];
  }
#pragma unroll
  for (int e = 0; e < 2; ++e) {
    int s = threadIdx.x + e * 256;
    float fs = (float)s;
    float ph = 0.f;
#pragma unroll
    for (int k = 0; k < 10; ++k) {
      float d = kt[k] - fs;
      ph += a[k] * __expf(-bv[k] * d * d);
    }
    phi_bf[(b * TS + t) * CTS + s] = f2bf(ph);
  }
}

// ---------------------------------------------------------------------------
// K5: att_w[t][b][h] = sum_s phi[b][t][s] * c_inp[s][b][h]. Per-b MFMA GEMM.
__global__ __launch_bounds__(256) void k_attw(
    const float* __restrict__ c_inp, const unsigned short* __restrict__ phi_bf,
    float* __restrict__ out_w, unsigned short* __restrict__ attw_bf) {
  int h0 = blockIdx.x * 64;
  int t0 = blockIdx.y * 64;
  int b  = blockIdx.z;
  int tid = threadIdx.x;
  int lane = tid & 63, wv = tid >> 6;
  int x = lane & 15, q = lane >> 4;
  __shared__ __align__(16) unsigned short Bt[64 * 40];  // [h_local][s_local], pad 40
  floatx4 acc[4];
#pragma unroll
  for (int m = 0; m < 4; ++m) acc[m] = (floatx4){0.f, 0.f, 0.f, 0.f};
  int s_l = tid >> 3, h8 = (tid & 7) * 8;
  for (int ss = 0; ss < 16; ++ss) {
    int s0 = ss * 32;
    const float* src = c_inp + ((s0 + s_l) * BB + b) * HH + h0 + h8;
    float4 v0 = *(const float4*)src;
    float4 v1 = *(const float4*)(src + 4);
    Bt[(h8 + 0) * 40 + s_l] = f2bf(v0.x);
    Bt[(h8 + 1) * 40 + s_l] = f2bf(v0.y);
    Bt[(h8 + 2) * 40 + s_l] = f2bf(v0.z);
    Bt[(h8 + 3) * 40 + s_l] = f2bf(v0.w);
    Bt[(h8 + 4) * 40 + s_l] = f2bf(v1.x);
    Bt[(h8 + 5) * 40 + s_l] = f2bf(v1.y);
    Bt[(h8 + 6) * 40 + s_l] = f2bf(v1.z);
    Bt[(h8 + 7) * 40 + s_l] = f2bf(v1.w);
    __syncthreads();
    short8 bfrag = *(const short8*)(Bt + (wv * 16 + x) * 40 + q * 8);
#pragma unroll
    for (int mt = 0; mt < 4; ++mt) {
      short8 af = *(const short8*)(phi_bf + (b * TS + t0 + mt * 16 + x) * CTS + s0 + q * 8);
      acc[mt] = __builtin_amdgcn_mfma_f32_16x16x32_bf16(af, bfrag, acc[mt], 0, 0, 0);
    }
    __syncthreads();
  }
#pragma unroll
  for (int mt = 0; mt < 4; ++mt)
#pragma unroll
    for (int r = 0; r < 4; ++r) {
      int t_l = mt * 16 + q * 4 + r;           // C/D: row = quad*4+reg
      int row = (t0 + t_l) * BB + b;
      int col = h0 + wv * 16 + x;              // C/D: col = lane&15
      float v = acc[mt][r];
      out_w[row * HH + col] = v;
      attw_bf[row * HH + col] = f2bf(v);
    }
}

// ---------------------------------------------------------------------------
// K6 v4: persistent GRU, all 32 worker WGs pinned to ONE XCD so the h exchange
// runs through that XCD's shared L2 (plain stores + sc0 loads), never MALL.
// Launch: 256 plain WGs; each buckets itself by HW_REG_XCC_ID; first XCD to
// fill 32 claims the job, everyone else exits.
// Waves specialize: kh = K-half (0: h-part from hsT, 1: w-part from awT),
// nh = N-half (32 of the WG's 64 gate-rows). gbuf aliases awT (LDS budget).
// Tiles are XOR-swizzled per row so ds_read_b128 A-fragments are conflict-free.
__global__ __launch_bounds__(256, 1) void k_seq(
    const unsigned short* __restrict__ attw_bf, const unsigned short* __restrict__ Wcat,
    const float* __restrict__ gru_init, const float* __restrict__ b_ih,
    const float* __restrict__ b_hh, unsigned short* __restrict__ h_buf,
    unsigned* __restrict__ flags, unsigned* __restrict__ ctl,
    float* __restrict__ hid_out) {
  __shared__ __align__(16) unsigned short hsT[64 * 512];   // h_{t-1} tile (swizzled)
  __shared__ __align__(16) unsigned short awT[64 * 512];   // attw_t tile (swizzled)
  __shared__ float bsum[64];
  __shared__ int sh_slot;
  float* const gbuf = (float*)awT;   // gbuf[2][64][66] aliased (33.8 KB < 64 KB)

  const int tid = threadIdx.x;

  // --- XCD-local slot discovery (device-scope atomics, one-time) ---
  if (tid == 0) {
    unsigned xcc = __builtin_amdgcn_s_getreg(6164) & 0xfu;  // hwreg(HW_REG_XCC_ID,0,4)
    unsigned s = atomicAdd(&ctl[1 + xcc], 1u);
    if (s == 31u) atomicCAS(&ctl[0], 0u, xcc + 1u);         // first full bucket wins
    unsigned ch;
    while ((ch = __hip_atomic_load(&ctl[0], __ATOMIC_RELAXED,
                                   __HIP_MEMORY_SCOPE_AGENT)) == 0u) {}
    sh_slot = (ch - 1u == xcc && s < 32u) ? (int)s : -1;
  }
  __syncthreads();
  const int w = sh_slot;
  if (w < 0) return;  // not a worker

  const int lane = tid & 63, wv = tid >> 6;
  const int x = lane & 15, q = lane >> 4;
  const int kh = wv & 1;    // K-half: 0 = h (K 0..511), 1 = w (K 512..1023)
  const int nh = wv >> 1;   // N-half: 32 gate-rows
  const int j0 = w * 16;

  // Weight B-fragments: rows (nh*2+nt)*512 + j0 + x, K-cols kh*512 + kk*32 + q*8.
  short8 wfrag[2][16];
#pragma unroll
  for (int nt = 0; nt < 2; ++nt) {
    const unsigned short* wr = Wcat + (size_t)((nh * 2 + nt) * 512 + j0 + x) * 1024 + kh * 512;
#pragma unroll
    for (int kk = 0; kk < 16; ++kk)
      wfrag[nt][kk] = *(const short8*)(wr + kk * 32 + q * 8);
  }
  if (tid < 64) {
    int g = tid >> 4, jl = tid & 15, j = j0 + jl;
    float v;
    if (g == 0)      v = b_ih[j] + b_hh[j];
    else if (g == 1) v = b_ih[512 + j] + b_hh[512 + j];
    else if (g == 2) v = b_ih[1024 + j];
    else             v = b_hh[1024 + j];
    bsum[tid] = v;
  }
  __syncthreads();
  const float bias0 = (kh == 0) ? bsum[nh * 32 + x] : 0.f;
  const float bias1 = (kh == 0) ? bsum[nh * 32 + 16 + x] : 0.f;

  // This thread's gate cells: (bo, jl0..+1), (bo+32, jl0..+1)
  const int bo = tid >> 3, jl0 = (tid & 7) * 2;
  float hp[4];
  hp[0] = gru_init[bo * HH + j0 + jl0];
  hp[1] = gru_init[bo * HH + j0 + jl0 + 1];
  hp[2] = gru_init[(bo + 32) * HH + j0 + jl0];
  hp[3] = gru_init[(bo + 32) * HH + j0 + jl0 + 1];

  // Publish init h into slot 0 (plain stores -> XCD L2 via write-through L1).
  {
    unsigned p0 = (unsigned)f2bf(hp[0]) | ((unsigned)f2bf(hp[1]) << 16);
    unsigned p1 = (unsigned)f2bf(hp[2]) | ((unsigned)f2bf(hp[3]) << 16);
    *(unsigned*)(h_buf + bo * HH + j0 + jl0) = p0;
    *(unsigned*)(h_buf + (bo + 32) * HH + j0 + jl0) = p1;
  }
  asm volatile("" ::: "memory");
  __builtin_amdgcn_s_waitcnt(0);   // stores L2-committed
  __syncthreads();
  if (tid == 0) flags[w * 32] = 1u;
  asm volatile("" ::: "memory");

  // Prefetch attw(0) tile into awT (async; XOR-swizzled rows).
#pragma unroll
  for (int i = 0; i < 16; ++i) {
    int b = wv * 16 + i;
    gll16_c(attw_bf + (size_t)b * 512 + ((lane ^ b) * 8), awT + b * 512);
  }

  for (int t = 0; t < TS; ++t) {
    // --- wait for all 32 workers to have published h_{t-1} ---
    if (tid < 32) {
      const unsigned* fp = flags + tid * 32;
      unsigned fv;
      do {
        asm volatile("global_load_dword %0, %1, off sc0\n\ts_waitcnt vmcnt(0)"
                     : "=v"(fv)
                     : "v"((unsigned long long)(uintptr_t)fp)
                     : "memory");
      } while (fv < (unsigned)(t + 1));
    }
    __syncthreads();

    // --- stage h_{t-1} into hsT (sc0: bypass L1, read fresh from XCD L2) ---
    const unsigned short* hsrc = h_buf + (size_t)(t & 3) * (BB * HH);
#pragma unroll
    for (int i = 0; i < 16; ++i) {
      int b = wv * 16 + i;
      gll16_sc0(hsrc + (size_t)b * 512 + ((lane ^ b) * 8), hsT + b * 512);
    }
    __builtin_amdgcn_s_waitcnt(0);   // h tile + attw tile resident in LDS
    __syncthreads();

    // --- MFMA: this wave's K-half against its 2 N-tiles ---
    floatx4 acc[4][2];
#pragma unroll
    for (int m = 0; m < 4; ++m) {
      acc[m][0] = (floatx4){bias0, bias0, bias0, bias0};
      acc[m][1] = (floatx4){bias1, bias1, bias1, bias1};
    }
    const unsigned short* tile = kh ? awT : hsT;
#pragma unroll
    for (int kk = 0; kk < 16; ++kk) {
#pragma unroll
      for (int m = 0; m < 4; ++m) {
        int row = m * 16 + x;
        int ch = ((kk * 4 + q) ^ row) & 63;       // de-swizzle
        short8 a = *(const short8*)(tile + row * 512 + ch * 8);
        acc[m][0] = __builtin_amdgcn_mfma_f32_16x16x32_bf16(a, wfrag[0][kk], acc[m][0], 0, 0, 0);
        acc[m][1] = __builtin_amdgcn_mfma_f32_16x16x32_bf16(a, wfrag[1][kk], acc[m][1], 0, 0, 0);
      }
    }
    __syncthreads();   // all tile reads done -> awT low half reusable as gbuf

    // --- scatter partial pre-activations: gbuf[kh][b][n] ---
    {
      float* gb = gbuf + kh * (64 * 66) ;
#pragma unroll
      for (int m = 0; m < 4; ++m)
#pragma unroll
        for (int nt = 0; nt < 2; ++nt)
#pragma unroll
          for (int r = 0; r < 4; ++r)
            gb[(m * 16 + q * 4 + r) * 66 + nh * 32 + nt * 16 + x] = acc[m][nt][r];
    }
    __syncthreads();

    // --- gates for this thread's 4 cells ---
    unsigned short* hdst = h_buf + (size_t)((t + 1) & 3) * (BB * HH);
    float hn_[4];
#pragma unroll
    for (int e = 0; e < 4; ++e) {
      int b = bo + (e >> 1) * 32, jl = jl0 + (e & 1);
      const float* g0 = gbuf + b * 66;
      const float* g1 = gbuf + 64 * 66 + b * 66;
      float rp = g0[jl]      + g1[jl];
      float zp = g0[16 + jl] + g1[16 + jl];
      float ip = g0[32 + jl] + g1[32 + jl];
      float hn = g0[48 + jl] + g1[48 + jl];
      float r_ = 1.f / (1.f + __expf(-rp));
      float z_ = 1.f / (1.f + __expf(-zp));
      float n_ = tanhf(ip + r_ * hn);
      hn_[e] = (1.f - z_) * n_ + z_ * hp[e];
    }
#pragma unroll
    for (int e = 0; e < 4; ++e) hp[e] = hn_[e];

    // --- outputs + publish h_t (plain stores -> XCD L2) ---
    *(float2*)(hid_out + ((size_t)t * BB + bo) * HH + j0 + jl0) =
        make_float2(hp[0], hp[1]);
    *(float2*)(hid_out + ((size_t)t * BB + bo + 32) * HH + j0 + jl0) =
        make_float2(hp[2], hp[3]);
    {
      unsigned p0 = (unsigned)f2bf(hp[0]) | ((unsigned)f2bf(hp[1]) << 16);
      unsigned p1 = (unsigned)f2bf(hp[2]) | ((unsigned)f2bf(hp[3]) << 16);
      *(unsigned*)(hdst + bo * HH + j0 + jl0) = p0;
      *(unsigned*)(hdst + (bo + 32) * HH + j0 + jl0) = p1;
    }
    asm volatile("" ::: "memory");
    __builtin_amdgcn_s_waitcnt(0);   // publishes L2-committed
    __syncthreads();
    if (tid == 0) flags[w * 32] = (unsigned)(t + 2);
    asm volatile("" ::: "memory");

    // --- prefetch attw(t+1) (async; overlaps everyone's flag wait) ---
    if (t + 1 < TS) {
      const unsigned short* aw = attw_bf + (size_t)(t + 1) * (BB * HH);
#pragma unroll
      for (int i = 0; i < 16; ++i) {
        int b = wv * 16 + i;
        gll16_c(aw + (size_t)b * 512 + ((lane ^ b) * 8), awT + b * 512);
      }
    }
  }
}

// ---------------------------------------------------------------------------
extern "C" void kernel_launch(void* const* d_in, const int* in_sizes, int n_in,
                              void* d_out, int out_size, void* d_ws, size_t ws_size,
                              hipStream_t stream) {
  const float* c_inp    = (const float*)d_in[0];
  const float* inp      = (const float*)d_in[1];
  const float* gru_init = (const float*)d_in[2];
  const float* att_init = (const float*)d_in[3];
  const float* Wa = (const float*)d_in[4];
  const float* ba = (const float*)d_in[5];
  const float* Wb = (const float*)d_in[6];
  const float* bvb = (const float*)d_in[7];
  const float* Wk = (const float*)d_in[8];
  const float* bk = (const float*)d_in[9];
  const float* W_ih = (const float*)d_in[10];
  const float* b_ih = (const float*)d_in[11];
  const float* W_hh = (const float*)d_in[12];
  const float* b_hh = (const float*)d_in[13];

  float* out_h = (float*)d_out;                     // hiddens [256,64,512]
  float* out_k = out_h + TS * BB * HH;              // att_k   [256,64,10]
  float* out_w = out_k + TS * BB * KK;              // att_w   [256,64,512]

  char* ws = (char*)d_ws;
  float* G             = (float*)(ws);                              //  2 MB used
  unsigned short* Wcat = (unsigned short*)(ws + 8388608);           //  4 MB
  unsigned short* phi  = (unsigned short*)(ws + 12582912);          // 16 MB
  unsigned short* awb  = (unsigned short*)(ws + 29360128);          // 16 MB
  unsigned short* hbuf = (unsigned short*)(ws + 46137344);          // 256 KB (4 slots)
  unsigned* flags      = (unsigned*)(ws + 46399488);                //  4 KB
  unsigned* ctl        = (unsigned*)(ws + 46403584);                //  64 B

  hipMemsetAsync(flags, 0, 8192, stream);  // flags + ctl
  hipLaunchKernelGGL(k_wcat, dim3(8192), dim3(256), 0, stream, W_ih, W_hh, Wcat);
  hipLaunchKernelGGL(k_abk, dim3(TS * BB), dim3(64), 0, stream,
                     inp, Wa, ba, Wb, bvb, Wk, bk, G);
  hipLaunchKernelGGL(k_cumsum, dim3(BB), dim3(256), 0, stream, G, att_init, out_k);
  hipLaunchKernelGGL(k_phi, dim3(TS, BB), dim3(256), 0, stream, G, out_k, phi);
  hipLaunchKernelGGL(k_attw, dim3(8, 4, BB), dim3(256), 0, stream, c_inp, phi, out_w, awb);
  hipLaunchKernelGGL(k_seq, dim3(256), dim3(256), 0, stream,
                     awb, Wcat, gru_init, b_ih, b_hh, hbuf, flags, ctl, out_h);
}